// Round 1
// baseline (246.501 us; speedup 1.0000x reference)
//
#include <hip/hip_runtime.h>
#include <math.h>

#define NB 64
#define NN 100
#define HH 128

static constexpr float EPSBN = 1e-5f;

// ---------------- adjacency: Ah = D^-1/2 (A|I) D^-1/2, rs = rowsum(Ah) ----------------
__global__ __launch_bounds__(256) void k_adj(const float* __restrict__ X,
                                             float* __restrict__ Ah,
                                             float* __restrict__ rs) {
    __shared__ float sX[NN * NN];
    __shared__ float sdinv[NN];
    const int b = blockIdx.x;
    const int tid = threadIdx.x;
    const float* Xb = X + b * NN * NN;
    for (int idx = tid; idx < NN * NN; idx += 256) sX[idx] = Xb[idx];
    __syncthreads();
    if (tid < NN) {
        float d = 0.f;
        for (int j = 0; j < NN; ++j) {
            float at = (j == tid) ? 1.f : (sX[tid * NN + j] != 0.f ? 1.f : 0.f);
            d += at;
        }
        sdinv[tid] = 1.0f / sqrtf(d);
    }
    __syncthreads();
    float* Ab = Ah + b * NN * NN;
    for (int idx = tid; idx < NN * NN; idx += 256) {
        int i = idx / NN, j = idx - i * NN;
        float at = (i == j) ? 1.f : (sX[idx] != 0.f ? 1.f : 0.f);
        Ab[idx] = sdinv[i] * at * sdinv[j];
    }
    if (tid < NN) {
        float s = 0.f;
        for (int j = 0; j < NN; ++j) {
            float at = (j == tid) ? 1.f : (sX[tid * NN + j] != 0.f ? 1.f : 0.f);
            s += at * sdinv[j];
        }
        rs[b * NN + tid] = sdinv[tid] * s;
    }
}

// ---------------- time MLP -> t_node -> u1[b,h], Dfull[b] ----------------
__global__ __launch_bounds__(128) void k_temb(
    const float* __restrict__ timev,
    const float* __restrict__ Wt1, const float* __restrict__ bt1,
    const float* __restrict__ Wt2, const float* __restrict__ bt2,
    const float* __restrict__ Wtn, const float* __restrict__ btn,
    const float* __restrict__ g_tn, const float* __restrict__ b_tn,
    const float* __restrict__ Wg1, const float* __restrict__ We1,
    const float* __restrict__ be1, const float* __restrict__ be0,
    const float* __restrict__ g_e0, const float* __restrict__ b_e0,
    float* __restrict__ u1, float* __restrict__ Dfull) {
    const int b = blockIdx.x, tid = threadIdx.x;
    __shared__ float s_temb[HH], s_h1[HH], s_h[HH], s_tn[NN];
    const float rinv = 1.0f / sqrtf(1.f + EPSBN);
    const float t = timev[b];
    // timestep embedding: half=64, freqs = exp(k * (-ln(10000)/63))
    {
        int k = tid & 63;
        float f = expf((float)k * (-logf(10000.f) / 63.f));
        float a = t * f;
        s_temb[tid] = (tid < 64) ? sinf(a) : cosf(a);
    }
    __syncthreads();
    float acc = bt1[tid];
    for (int q = 0; q < HH; ++q) acc = fmaf(s_temb[q], Wt1[q * HH + tid], acc);
    s_h1[tid] = fmaxf(acc, 0.f);
    __syncthreads();
    acc = bt2[tid];
    for (int q = 0; q < HH; ++q) acc = fmaf(s_h1[q], Wt2[q * HH + tid], acc);
    s_h[tid] = acc;
    __syncthreads();
    if (tid < NN) {
        float v = btn[tid];
        for (int q = 0; q < HH; ++q) v = fmaf(s_h[q], Wtn[q * NN + tid], v);
        s_tn[tid] = fmaxf(fmaf(g_tn[tid] * rinv, v, b_tn[tid]), 0.f);
    }
    __syncthreads();
    // u1[b,h] = t_node[b,:] @ Wg1[N:, h]
    acc = 0.f;
    for (int n = 0; n < NN; ++n) acc = fmaf(s_tn[n], Wg1[(NN + n) * HH + tid], acc);
    u1[b * HH + tid] = acc;
    if (tid == 0) {
        float tp = 0.f;  // h @ We1[H:]
        for (int q = 0; q < HH; ++q) tp = fmaf(s_h[q], We1[HH + q], tp);
        float K = 0.f;  // batch-independent bias folding
        for (int hh = 0; hh < HH; ++hh)
            K += (be0[hh] * g_e0[hh] * rinv + b_e0[hh]) * We1[hh];
        Dfull[b] = tp + K + be1[0];
    }
}

// ---------------- vi = We0[:H] @ c, vj = We0[H:] @ c, c = g_e0*We1[:H]/r ----------------
__global__ __launch_bounds__(128) void k_vij(const float* __restrict__ We0,
                                             const float* __restrict__ We1,
                                             const float* __restrict__ g_e0,
                                             float* __restrict__ vi, float* __restrict__ vj) {
    __shared__ float sc[HH];
    const int tid = threadIdx.x;
    const float rinv = 1.0f / sqrtf(1.f + EPSBN);
    sc[tid] = g_e0[tid] * We1[tid] * rinv;
    __syncthreads();
    float a = 0.f, c = 0.f;
    for (int hh = 0; hh < HH; ++hh) {
        a = fmaf(We0[tid * HH + hh], sc[hh], a);
        c = fmaf(We0[(HH + tid) * HH + hh], sc[hh], c);
    }
    vi[tid] = a;
    vj[tid] = c;
}

// ---------------- layer 1: relu(bn(Ah@Wg1[:N] + rs*u1 + bg1)) ----------------
// grid (4, B), block 128: 25 output rows per block, h per lane.
// Ah reads are wave-uniform (blockIdx/loop-index addressing) -> scalar cache.
__global__ __launch_bounds__(128) void k_gemm1(
    const float* __restrict__ Ah, const float* __restrict__ Wg1,
    const float* __restrict__ u1, const float* __restrict__ rs,
    const float* __restrict__ bg1, const float* __restrict__ g1,
    const float* __restrict__ bb1, float* __restrict__ out) {
    const int b = blockIdx.y, r0 = blockIdx.x * 25, h = threadIdx.x;
    const float rinv = 1.0f / sqrtf(1.f + EPSBN);
    const float* Ab = Ah + b * NN * NN;
    float acc[25];
#pragma unroll
    for (int r = 0; r < 25; ++r) acc[r] = 0.f;
    for (int j4 = 0; j4 < 25; ++j4) {
        const int j = j4 * 4;
        float w0 = Wg1[(j + 0) * HH + h];
        float w1 = Wg1[(j + 1) * HH + h];
        float w2 = Wg1[(j + 2) * HH + h];
        float w3 = Wg1[(j + 3) * HH + h];
#pragma unroll
        for (int r = 0; r < 25; ++r) {
            float4 av = *reinterpret_cast<const float4*>(Ab + (r0 + r) * NN + j);
            acc[r] = fmaf(av.x, w0, acc[r]);
            acc[r] = fmaf(av.y, w1, acc[r]);
            acc[r] = fmaf(av.z, w2, acc[r]);
            acc[r] = fmaf(av.w, w3, acc[r]);
        }
    }
    const float uh = u1[b * HH + h];
    const float gs = g1[h] * rinv, bbh = bb1[h], bgh = bg1[h];
#pragma unroll
    for (int r = 0; r < 25; ++r) {
        int i = r0 + r;
        float y = acc[r] + rs[b * NN + i] * uh + bgh;
        out[b * NN * HH + i * HH + h] = fmaxf(fmaf(gs, y, bbh), 0.f);
    }
}

// ---------------- z = x @ W ----------------
__global__ __launch_bounds__(128) void k_xw(const float* __restrict__ xin,
                                            const float* __restrict__ W,
                                            float* __restrict__ z) {
    const int b = blockIdx.y, r0 = blockIdx.x * 25, h = threadIdx.x;
    const float* xb = xin + b * NN * HH;
    float acc[25];
#pragma unroll
    for (int r = 0; r < 25; ++r) acc[r] = 0.f;
    for (int k4 = 0; k4 < 32; ++k4) {
        const int k = k4 * 4;
        float w0 = W[(k + 0) * HH + h];
        float w1 = W[(k + 1) * HH + h];
        float w2 = W[(k + 2) * HH + h];
        float w3 = W[(k + 3) * HH + h];
#pragma unroll
        for (int r = 0; r < 25; ++r) {
            float4 xv = *reinterpret_cast<const float4*>(xb + (r0 + r) * HH + k);
            acc[r] = fmaf(xv.x, w0, acc[r]);
            acc[r] = fmaf(xv.y, w1, acc[r]);
            acc[r] = fmaf(xv.z, w2, acc[r]);
            acc[r] = fmaf(xv.w, w3, acc[r]);
        }
    }
#pragma unroll
    for (int r = 0; r < 25; ++r)
        z[b * NN * HH + (r0 + r) * HH + h] = acc[r];
}

// ---------------- x_out = relu(bn(Ah@z + bg)) ----------------
__global__ __launch_bounds__(128) void k_ah(
    const float* __restrict__ Ah, const float* __restrict__ z,
    const float* __restrict__ bg, const float* __restrict__ g,
    const float* __restrict__ bb, float* __restrict__ out) {
    const int b = blockIdx.y, r0 = blockIdx.x * 25, h = threadIdx.x;
    const float rinv = 1.0f / sqrtf(1.f + EPSBN);
    const float* Ab = Ah + b * NN * NN;
    const float* zb = z + b * NN * HH;
    float acc[25];
#pragma unroll
    for (int r = 0; r < 25; ++r) acc[r] = 0.f;
    for (int j4 = 0; j4 < 25; ++j4) {
        const int j = j4 * 4;
        float w0 = zb[(j + 0) * HH + h];
        float w1 = zb[(j + 1) * HH + h];
        float w2 = zb[(j + 2) * HH + h];
        float w3 = zb[(j + 3) * HH + h];
#pragma unroll
        for (int r = 0; r < 25; ++r) {
            float4 av = *reinterpret_cast<const float4*>(Ab + (r0 + r) * NN + j);
            acc[r] = fmaf(av.x, w0, acc[r]);
            acc[r] = fmaf(av.y, w1, acc[r]);
            acc[r] = fmaf(av.z, w2, acc[r]);
            acc[r] = fmaf(av.w, w3, acc[r]);
        }
    }
    const float gs = g[h] * rinv, bbh = bb[h], bgh = bg[h];
#pragma unroll
    for (int r = 0; r < 25; ++r) {
        float y = acc[r] + bgh;
        out[b * NN * HH + (r0 + r) * HH + h] = fmaxf(fmaf(gs, y, bbh), 0.f);
    }
}

// ---------------- si[b,i] = x3[b,i]·vi, sj[b,i] = x3[b,i]·vj ----------------
__global__ __launch_bounds__(256) void k_sisj(const float* __restrict__ x3,
                                              const float* __restrict__ vi,
                                              const float* __restrict__ vj,
                                              float* __restrict__ si,
                                              float* __restrict__ sj) {
    const int idx = blockIdx.x * 256 + threadIdx.x;
    if (idx >= NB * NN) return;
    const float4* row = reinterpret_cast<const float4*>(x3 + (size_t)idx * HH);
    float a = 0.f, c = 0.f;
#pragma unroll
    for (int q = 0; q < 32; ++q) {
        float4 v = row[q];
        a = fmaf(v.x, vi[4 * q + 0], a); c = fmaf(v.x, vj[4 * q + 0], c);
        a = fmaf(v.y, vi[4 * q + 1], a); c = fmaf(v.y, vj[4 * q + 1], c);
        a = fmaf(v.z, vi[4 * q + 2], a); c = fmaf(v.z, vj[4 * q + 2], c);
        a = fmaf(v.w, vi[4 * q + 3], a); c = fmaf(v.w, vj[4 * q + 3], c);
    }
    si[idx] = a;
    sj[idx] = c;
}

// ---------------- out[b,i,j] = (i!=j) * bn(si+sj+D) ----------------
__global__ __launch_bounds__(256) void k_out(const float* __restrict__ si,
                                             const float* __restrict__ sj,
                                             const float* __restrict__ Dfull,
                                             const float* __restrict__ g_e1,
                                             const float* __restrict__ b_e1,
                                             float* __restrict__ out) {
    const int gid = blockIdx.x * 256 + threadIdx.x;
    if (gid >= NB * NN * NN) return;
    const float rinv = 1.0f / sqrtf(1.f + EPSBN);
    int b = gid / (NN * NN);
    int rem = gid - b * NN * NN;
    int i = rem / NN;
    int j = rem - i * NN;
    float s = si[b * NN + i] + sj[b * NN + j] + Dfull[b];
    float v = fmaf(g_e1[0] * rinv, s, b_e1[0]);
    out[gid] = (i == j) ? 0.f : v;
}

extern "C" void kernel_launch(void* const* d_in, const int* in_sizes, int n_in,
                              void* d_out, int out_size, void* d_ws, size_t ws_size,
                              hipStream_t stream) {
    const float* X    = (const float*)d_in[0];
    const float* timev= (const float*)d_in[1];
    const float* Wt1  = (const float*)d_in[2];
    const float* bt1  = (const float*)d_in[3];
    const float* Wt2  = (const float*)d_in[4];
    const float* bt2  = (const float*)d_in[5];
    const float* Wtn  = (const float*)d_in[6];
    const float* btn  = (const float*)d_in[7];
    const float* g_tn = (const float*)d_in[8];
    const float* b_tn = (const float*)d_in[9];
    const float* Wg1  = (const float*)d_in[10];
    const float* bg1  = (const float*)d_in[11];
    const float* g1   = (const float*)d_in[12];
    const float* bb1  = (const float*)d_in[13];
    const float* Wg2  = (const float*)d_in[14];
    const float* bg2  = (const float*)d_in[15];
    const float* g2   = (const float*)d_in[16];
    const float* bb2  = (const float*)d_in[17];
    const float* Wg3  = (const float*)d_in[18];
    const float* bg3  = (const float*)d_in[19];
    const float* g3   = (const float*)d_in[20];
    const float* bb3  = (const float*)d_in[21];
    const float* We0  = (const float*)d_in[22];
    const float* be0  = (const float*)d_in[23];
    const float* g_e0 = (const float*)d_in[24];
    const float* b_e0 = (const float*)d_in[25];
    const float* We1  = (const float*)d_in[26];
    const float* be1  = (const float*)d_in[27];
    const float* g_e1 = (const float*)d_in[28];
    const float* b_e1 = (const float*)d_in[29];

    float* ws = (float*)d_ws;
    float* Ah    = ws;            // 640000
    float* rs    = Ah + 640000;   // 6400
    float* u1    = rs + 6400;     // 8192
    float* Dfull = u1 + 8192;     // 64
    float* vi    = Dfull + 64;    // 128
    float* vj    = vi + 128;      // 128
    float* si    = vj + 128;      // 6400
    float* sj    = si + 6400;     // 6400
    float* buf0  = sj + 6400;     // 819200
    float* buf1  = buf0 + 819200; // 819200  (total ~9.2 MB)

    k_adj<<<dim3(NB), dim3(256), 0, stream>>>(X, Ah, rs);
    k_temb<<<dim3(NB), dim3(128), 0, stream>>>(timev, Wt1, bt1, Wt2, bt2, Wtn, btn,
                                               g_tn, b_tn, Wg1, We1, be1, be0, g_e0,
                                               b_e0, u1, Dfull);
    k_vij<<<dim3(1), dim3(128), 0, stream>>>(We0, We1, g_e0, vi, vj);

    k_gemm1<<<dim3(4, NB), dim3(128), 0, stream>>>(Ah, Wg1, u1, rs, bg1, g1, bb1, buf0);
    k_xw<<<dim3(4, NB), dim3(128), 0, stream>>>(buf0, Wg2, buf1);
    k_ah<<<dim3(4, NB), dim3(128), 0, stream>>>(Ah, buf1, bg2, g2, bb2, buf0);
    k_xw<<<dim3(4, NB), dim3(128), 0, stream>>>(buf0, Wg3, buf1);
    k_ah<<<dim3(4, NB), dim3(128), 0, stream>>>(Ah, buf1, bg3, g3, bb3, buf0);

    k_sisj<<<dim3(25), dim3(256), 0, stream>>>(buf0, vi, vj, si, sj);
    k_out<<<dim3(2500), dim3(256), 0, stream>>>(si, sj, Dfull, g_e1, b_e1, (float*)d_out);
}

// Round 2
// 119.893 us; speedup vs baseline: 2.0560x; 2.0560x over previous
//
#include <hip/hip_runtime.h>
#include <math.h>

#define NB 64
#define NN 100
#define HH 128
#define HC 16
#define NCH 8

static constexpr float EPSBN = 1e-5f;

// ---------------- adjacency: Ah = D^-1/2 (A|I) D^-1/2, rs = rowsum(Ah) ----------------
__global__ __launch_bounds__(256) void k_adj(const float* __restrict__ X,
                                             float* __restrict__ Ah,
                                             float* __restrict__ rs) {
    __shared__ float sX[NN * NN];
    __shared__ float sdinv[NN];
    const int b = blockIdx.x;
    const int tid = threadIdx.x;
    const float* Xb = X + b * NN * NN;
    for (int idx = tid; idx < NN * NN; idx += 256) sX[idx] = Xb[idx];
    __syncthreads();
    if (tid < NN) {
        float d = 0.f;
        for (int j = 0; j < NN; ++j) {
            float at = (j == tid) ? 1.f : (sX[tid * NN + j] != 0.f ? 1.f : 0.f);
            d += at;
        }
        sdinv[tid] = 1.0f / sqrtf(d);
    }
    __syncthreads();
    float* Ab = Ah + b * NN * NN;
    for (int idx = tid; idx < NN * NN; idx += 256) {
        int i = idx / NN, j = idx - i * NN;
        float at = (i == j) ? 1.f : (sX[idx] != 0.f ? 1.f : 0.f);
        Ab[idx] = sdinv[i] * at * sdinv[j];
    }
    if (tid < NN) {
        float s = 0.f;
        for (int j = 0; j < NN; ++j) {
            float at = (j == tid) ? 1.f : (sX[tid * NN + j] != 0.f ? 1.f : 0.f);
            s += at * sdinv[j];
        }
        rs[b * NN + tid] = sdinv[tid] * s;
    }
}

// ---------------- time MLP -> u1[b,h], Dfull[b]; block NB does vi/vj ----------------
__global__ __launch_bounds__(128) void k_temb(
    const float* __restrict__ timev,
    const float* __restrict__ Wt1, const float* __restrict__ bt1,
    const float* __restrict__ Wt2, const float* __restrict__ bt2,
    const float* __restrict__ Wtn, const float* __restrict__ btn,
    const float* __restrict__ g_tn, const float* __restrict__ b_tn,
    const float* __restrict__ Wg1, const float* __restrict__ We0,
    const float* __restrict__ We1,
    const float* __restrict__ be1, const float* __restrict__ be0,
    const float* __restrict__ g_e0, const float* __restrict__ b_e0,
    float* __restrict__ u1, float* __restrict__ Dfull,
    float* __restrict__ vi, float* __restrict__ vj) {
    const int tid = threadIdx.x;
    const float rinv = 1.0f / sqrtf(1.f + EPSBN);
    if (blockIdx.x == NB) {
        // vi = We0[:H] @ c, vj = We0[H:] @ c, c = g_e0*We1[:H]*rinv
        __shared__ float sc[HH];
        sc[tid] = g_e0[tid] * We1[tid] * rinv;
        __syncthreads();
        float a = 0.f, cc = 0.f;
        for (int hh = 0; hh < HH; ++hh) {
            a = fmaf(We0[tid * HH + hh], sc[hh], a);
            cc = fmaf(We0[(HH + tid) * HH + hh], sc[hh], cc);
        }
        vi[tid] = a;
        vj[tid] = cc;
        return;
    }
    const int b = blockIdx.x;
    __shared__ float s_temb[HH], s_h1[HH], s_h[HH], s_tn[NN];
    const float t = timev[b];
    {
        int k = tid & 63;
        float f = expf((float)k * (-logf(10000.f) / 63.f));
        float a = t * f;
        s_temb[tid] = (tid < 64) ? sinf(a) : cosf(a);
    }
    __syncthreads();
    float acc = bt1[tid];
    for (int q = 0; q < HH; ++q) acc = fmaf(s_temb[q], Wt1[q * HH + tid], acc);
    s_h1[tid] = fmaxf(acc, 0.f);
    __syncthreads();
    acc = bt2[tid];
    for (int q = 0; q < HH; ++q) acc = fmaf(s_h1[q], Wt2[q * HH + tid], acc);
    s_h[tid] = acc;
    __syncthreads();
    if (tid < NN) {
        float v = btn[tid];
        for (int q = 0; q < HH; ++q) v = fmaf(s_h[q], Wtn[q * NN + tid], v);
        s_tn[tid] = fmaxf(fmaf(g_tn[tid] * rinv, v, b_tn[tid]), 0.f);
    }
    __syncthreads();
    acc = 0.f;
    for (int n = 0; n < NN; ++n) acc = fmaf(s_tn[n], Wg1[(NN + n) * HH + tid], acc);
    u1[b * HH + tid] = acc;
    if (tid == 0) {
        float tp = 0.f;
        for (int q = 0; q < HH; ++q) tp = fmaf(s_h[q], We1[HH + q], tp);
        float K = 0.f;
        for (int hh = 0; hh < HH; ++hh)
            K += (be0[hh] * g_e0[hh] * rinv + b_e0[hh]) * We1[hh];
        Dfull[b] = tp + K + be1[0];
    }
}

// ---------------- layer 1: out = relu(bn(Ah@Wg1[:N,hc] + rs*u1 + bg1)) ----------------
// grid (8, 64), block 256 = (c=t&15, jg=t>>4); 7 rows per thread (ragged).
__global__ __launch_bounds__(256) void k_l1(
    const float* __restrict__ Ah, const float* __restrict__ Wg1,
    const float* __restrict__ u1, const float* __restrict__ rs,
    const float* __restrict__ bg1, const float* __restrict__ g1,
    const float* __restrict__ bb1, float* __restrict__ out) {
    __shared__ float sZ[NN * HC];
    const int b = blockIdx.y, hc = blockIdx.x * HC;
    const int t = threadIdx.x, c = t & 15, jg = t >> 4;
    for (int idx = t; idx < NN * HC; idx += 256) {
        int j = idx >> 4, cc = idx & 15;
        sZ[idx] = Wg1[j * HH + hc + cc];
    }
    __syncthreads();
    const float* __restrict__ Ab = Ah + b * NN * NN;
    const int r6 = (jg < 4) ? 96 + jg : jg;  // dummy row for jg>=4 (not written)
    float acc[7];
#pragma unroll
    for (int q = 0; q < 7; ++q) acc[q] = 0.f;
    for (int j = 0; j < NN; j += 4) {
        float z0 = sZ[(j + 0) * 16 + c];
        float z1 = sZ[(j + 1) * 16 + c];
        float z2 = sZ[(j + 2) * 16 + c];
        float z3 = sZ[(j + 3) * 16 + c];
#pragma unroll
        for (int q = 0; q < 7; ++q) {
            const int i = (q == 6) ? r6 : jg + 16 * q;
            float4 a4 = *reinterpret_cast<const float4*>(Ab + i * NN + j);
            acc[q] = fmaf(a4.x, z0, acc[q]);
            acc[q] = fmaf(a4.y, z1, acc[q]);
            acc[q] = fmaf(a4.z, z2, acc[q]);
            acc[q] = fmaf(a4.w, z3, acc[q]);
        }
    }
    const int hh = hc + c;
    const float rinv = 1.0f / sqrtf(1.f + EPSBN);
    const float gs = g1[hh] * rinv, bbh = bb1[hh], bgh = bg1[hh];
    const float uh = u1[b * HH + hh];
#pragma unroll
    for (int q = 0; q < 7; ++q) {
        const int i = (q == 6) ? r6 : jg + 16 * q;
        const bool valid = (q < 6) || (jg < 4);
        float y = acc[q] + rs[b * NN + i] * uh + bgh;
        if (valid) out[b * NN * HH + i * HH + hh] = fmaxf(fmaf(gs, y, bbh), 0.f);
    }
}

// ---------------- fused layer: z = x@W[:,hc] (LDS), out = relu(bn(Ah@z + bg)) ----------
// LAST: skip global out; write 16-lane-reduced partial si/sj instead.
template <bool LAST>
__global__ __launch_bounds__(256) void k_layer(
    const float* __restrict__ Ah, const float* __restrict__ xin,
    const float* __restrict__ W, const float* __restrict__ bg,
    const float* __restrict__ g, const float* __restrict__ bb,
    const float* __restrict__ vi, const float* __restrict__ vj,
    float* __restrict__ out, float* __restrict__ psi, float* __restrict__ psj) {
    __shared__ float sW[HC * 132];  // [c][k], pad 132 -> 2-way-free b128 reads
    __shared__ float sZ[NN * HC];   // [j][c]
    const int b = blockIdx.y, hcb = blockIdx.x, hc = hcb * HC;
    const int t = threadIdx.x, c = t & 15, jg = t >> 4;
    for (int idx = t; idx < HH * HC; idx += 256) {
        int cc = idx & 15, k = idx >> 4;
        sW[cc * 132 + k] = W[k * HH + hc + cc];
    }
    __syncthreads();
    const float* __restrict__ xb = xin + b * NN * HH;
    const int r6 = (jg < 4) ? 96 + jg : jg;
    float acc[7];
#pragma unroll
    for (int q = 0; q < 7; ++q) acc[q] = 0.f;
    for (int k = 0; k < HH; k += 4) {
        float4 w = *reinterpret_cast<const float4*>(&sW[c * 132 + k]);
#pragma unroll
        for (int q = 0; q < 7; ++q) {
            const int i = (q == 6) ? r6 : jg + 16 * q;
            float4 xv = *reinterpret_cast<const float4*>(xb + i * HH + k);
            acc[q] = fmaf(xv.x, w.x, acc[q]);
            acc[q] = fmaf(xv.y, w.y, acc[q]);
            acc[q] = fmaf(xv.z, w.z, acc[q]);
            acc[q] = fmaf(xv.w, w.w, acc[q]);
        }
    }
#pragma unroll
    for (int q = 0; q < 7; ++q) {
        const int i = (q == 6) ? r6 : jg + 16 * q;
        if (q < 6 || jg < 4) sZ[i * 16 + c] = acc[q];
    }
    __syncthreads();
#pragma unroll
    for (int q = 0; q < 7; ++q) acc[q] = 0.f;
    const float* __restrict__ Ab = Ah + b * NN * NN;
    for (int j = 0; j < NN; j += 4) {
        float z0 = sZ[(j + 0) * 16 + c];
        float z1 = sZ[(j + 1) * 16 + c];
        float z2 = sZ[(j + 2) * 16 + c];
        float z3 = sZ[(j + 3) * 16 + c];
#pragma unroll
        for (int q = 0; q < 7; ++q) {
            const int i = (q == 6) ? r6 : jg + 16 * q;
            float4 a4 = *reinterpret_cast<const float4*>(Ab + i * NN + j);
            acc[q] = fmaf(a4.x, z0, acc[q]);
            acc[q] = fmaf(a4.y, z1, acc[q]);
            acc[q] = fmaf(a4.z, z2, acc[q]);
            acc[q] = fmaf(a4.w, z3, acc[q]);
        }
    }
    const int hh = hc + c;
    const float rinv = 1.0f / sqrtf(1.f + EPSBN);
    const float gs = g[hh] * rinv, bbh = bb[hh], bgh = bg[hh];
    float vih = 0.f, vjh = 0.f;
    if (LAST) { vih = vi[hh]; vjh = vj[hh]; }
#pragma unroll
    for (int q = 0; q < 7; ++q) {
        const int i = (q == 6) ? r6 : jg + 16 * q;
        const bool valid = (q < 6) || (jg < 4);
        float y = fmaxf(fmaf(gs, acc[q] + bgh, bbh), 0.f);
        if (LAST) {
            float pi = y * vih, pj = y * vjh;
#pragma unroll
            for (int off = 1; off < 16; off <<= 1) {
                pi += __shfl_xor(pi, off, 16);
                pj += __shfl_xor(pj, off, 16);
            }
            if (c == 0 && valid) {
                psi[(b * NN + i) * NCH + hcb] = pi;
                psj[(b * NN + i) * NCH + hcb] = pj;
            }
        } else {
            if (valid) out[b * NN * HH + i * HH + hh] = y;
        }
    }
}

// ---------------- out[b,i,j] = (i!=j) * bn(si+sj+D); sums the 8 partials -------------
// grid (4, 64): block covers i in [x*25, x*25+25), all j.
__global__ __launch_bounds__(256) void k_out(
    const float* __restrict__ psi, const float* __restrict__ psj,
    const float* __restrict__ Dfull, const float* __restrict__ g_e1,
    const float* __restrict__ b_e1, float* __restrict__ outp) {
    __shared__ float ssi[25], ssj[NN];
    const int b = blockIdx.y, i0 = blockIdx.x * 25;
    const int t = threadIdx.x;
    if (t < NN) {
        float s = 0.f;
        const float* p = psj + (b * NN + t) * NCH;
#pragma unroll
        for (int q = 0; q < NCH; ++q) s += p[q];
        ssj[t] = s;
    }
    if (t >= 128 && t < 128 + 25) {
        int i = t - 128;
        float s = 0.f;
        const float* p = psi + (b * NN + i0 + i) * NCH;
#pragma unroll
        for (int q = 0; q < NCH; ++q) s += p[q];
        ssi[i] = s;
    }
    __syncthreads();
    const float rinv = 1.0f / sqrtf(1.f + EPSBN);
    const float D = Dfull[b], ge = g_e1[0] * rinv, be = b_e1[0];
    float* ob = outp + b * NN * NN + i0 * NN;
    for (int e = t; e < 25 * NN; e += 256) {
        int ii = e / NN, j = e - ii * NN;
        float v = fmaf(ge, ssi[ii] + ssj[j] + D, be);
        ob[e] = (i0 + ii == j) ? 0.f : v;
    }
}

extern "C" void kernel_launch(void* const* d_in, const int* in_sizes, int n_in,
                              void* d_out, int out_size, void* d_ws, size_t ws_size,
                              hipStream_t stream) {
    const float* X    = (const float*)d_in[0];
    const float* timev= (const float*)d_in[1];
    const float* Wt1  = (const float*)d_in[2];
    const float* bt1  = (const float*)d_in[3];
    const float* Wt2  = (const float*)d_in[4];
    const float* bt2  = (const float*)d_in[5];
    const float* Wtn  = (const float*)d_in[6];
    const float* btn  = (const float*)d_in[7];
    const float* g_tn = (const float*)d_in[8];
    const float* b_tn = (const float*)d_in[9];
    const float* Wg1  = (const float*)d_in[10];
    const float* bg1  = (const float*)d_in[11];
    const float* g1   = (const float*)d_in[12];
    const float* bb1  = (const float*)d_in[13];
    const float* Wg2  = (const float*)d_in[14];
    const float* bg2  = (const float*)d_in[15];
    const float* g2   = (const float*)d_in[16];
    const float* bb2  = (const float*)d_in[17];
    const float* Wg3  = (const float*)d_in[18];
    const float* bg3  = (const float*)d_in[19];
    const float* g3   = (const float*)d_in[20];
    const float* bb3  = (const float*)d_in[21];
    const float* We0  = (const float*)d_in[22];
    const float* be0  = (const float*)d_in[23];
    const float* g_e0 = (const float*)d_in[24];
    const float* b_e0 = (const float*)d_in[25];
    const float* We1  = (const float*)d_in[26];
    const float* be1  = (const float*)d_in[27];
    const float* g_e1 = (const float*)d_in[28];
    const float* b_e1 = (const float*)d_in[29];

    float* ws = (float*)d_ws;
    float* Ah    = ws;            // 640000
    float* rs    = Ah + 640000;   // 6400
    float* u1    = rs + 6400;     // 8192
    float* Dfull = u1 + 8192;     // 64
    float* vi    = Dfull + 64;    // 128
    float* vj    = vi + 128;      // 128
    float* x1    = vj + 128;      // 819200 (layer1 out; dead after k_l2 -> psi/psj alias)
    float* x2    = x1 + 819200;   // 819200 (layer2 out)
    float* psi   = x1;            // 51200 (aliases dead x1)
    float* psj   = x1 + 51200;    // 51200

    k_adj<<<dim3(NB), dim3(256), 0, stream>>>(X, Ah, rs);
    k_temb<<<dim3(NB + 1), dim3(128), 0, stream>>>(timev, Wt1, bt1, Wt2, bt2, Wtn, btn,
                                                   g_tn, b_tn, Wg1, We0, We1, be1, be0,
                                                   g_e0, b_e0, u1, Dfull, vi, vj);

    k_l1<<<dim3(NCH, NB), dim3(256), 0, stream>>>(Ah, Wg1, u1, rs, bg1, g1, bb1, x1);
    k_layer<false><<<dim3(NCH, NB), dim3(256), 0, stream>>>(Ah, x1, Wg2, bg2, g2, bb2,
                                                            nullptr, nullptr, x2,
                                                            nullptr, nullptr);
    k_layer<true><<<dim3(NCH, NB), dim3(256), 0, stream>>>(Ah, x2, Wg3, bg3, g3, bb3,
                                                           vi, vj, nullptr, psi, psj);

    k_out<<<dim3(4, NB), dim3(256), 0, stream>>>(psi, psj, Dfull, g_e1, b_e1,
                                                 (float*)d_out);
}

// Round 3
// 103.818 us; speedup vs baseline: 2.3744x; 1.1548x over previous
//
#include <hip/hip_runtime.h>
#include <math.h>

#define NB 64
#define NN 100
#define HH 128
#define HC 16
#define NCH 8

static constexpr float EPSBN = 1e-5f;

// ============ fused setup: adjacency (blocks 0-255), time MLP (256-319), vij (320) ====
__global__ __launch_bounds__(256) void k_setup(
    const float* __restrict__ X, const float* __restrict__ timev,
    const float* __restrict__ Wt1, const float* __restrict__ bt1,
    const float* __restrict__ Wt2, const float* __restrict__ bt2,
    const float* __restrict__ Wtn, const float* __restrict__ btn,
    const float* __restrict__ g_tn, const float* __restrict__ b_tn,
    const float* __restrict__ Wg1, const float* __restrict__ We0,
    const float* __restrict__ We1, const float* __restrict__ be1,
    const float* __restrict__ be0, const float* __restrict__ g_e0,
    const float* __restrict__ b_e0,
    float* __restrict__ Ah, float* __restrict__ rs,
    float* __restrict__ u1, float* __restrict__ Dfull,
    float* __restrict__ vi, float* __restrict__ vj) {
    __shared__ float sBuf[NN * NN];
    __shared__ float sdinv[128];
    const int bx = blockIdx.x, t = threadIdx.x;
    const float rinv = 1.0f / sqrtf(1.f + EPSBN);

    if (bx < 4 * NB) {
        // ---- adjacency: block (b, s) writes rows [25s, 25s+25) of Ah + rs ----
        const int b = bx >> 2, s = bx & 3;
        const float* Xb = X + b * NN * NN;
        float4* s4 = (float4*)sBuf;
        const float4* X4 = (const float4*)Xb;
        for (int idx = t; idx < NN * NN / 4; idx += 256) s4[idx] = X4[idx];
        __syncthreads();
        if (t < NN) {
            float deg = 0.f;
            const float4* row = (const float4*)(sBuf + t * NN);
            for (int q = 0; q < 25; ++q) {
                float4 v = row[q];
                deg += (v.x != 0.f ? 1.f : 0.f) + (v.y != 0.f ? 1.f : 0.f) +
                       (v.z != 0.f ? 1.f : 0.f) + (v.w != 0.f ? 1.f : 0.f);
            }
            if (sBuf[t * NN + t] == 0.f) deg += 1.f;  // self-loop if missing
            sdinv[t] = 1.0f / sqrtf(deg);
        }
        __syncthreads();
        float* Ab = Ah + b * NN * NN;
        const int i0 = s * 25;
        for (int idx = t; idx < 25 * NN; idx += 256) {
            int il = idx / NN, j = idx - il * NN;
            int i = i0 + il;
            float at = (i == j) ? 1.f : (sBuf[i * NN + j] != 0.f ? 1.f : 0.f);
            Ab[i * NN + j] = sdinv[i] * at * sdinv[j];
        }
        if (t < 25) {
            int i = i0 + t;
            float ssum = 0.f;
            for (int j = 0; j < NN; ++j) {
                float at = (i == j) ? 1.f : (sBuf[i * NN + j] != 0.f ? 1.f : 0.f);
                ssum += at * sdinv[j];
            }
            rs[b * NN + i] = sdinv[i] * ssum;
        }
        return;
    }
    if (bx < 4 * NB + NB) {
        // ---- time MLP ----
        const int b = bx - 4 * NB;
        float* s_temb = sBuf;
        float* s_h1 = sBuf + 128;
        float* s_h = sBuf + 256;
        float* s_tn = sBuf + 384;
        const float tt = timev[b];
        if (t < 128) {
            int k = t & 63;
            float f = expf((float)k * (-logf(10000.f) / 63.f));
            float a = tt * f;
            s_temb[t] = (t < 64) ? sinf(a) : cosf(a);
        }
        __syncthreads();
        if (t < 128) {
            float acc = bt1[t];
            for (int q = 0; q < HH; ++q) acc = fmaf(s_temb[q], Wt1[q * HH + t], acc);
            s_h1[t] = fmaxf(acc, 0.f);
        }
        __syncthreads();
        if (t < 128) {
            float acc = bt2[t];
            for (int q = 0; q < HH; ++q) acc = fmaf(s_h1[q], Wt2[q * HH + t], acc);
            s_h[t] = acc;
        }
        __syncthreads();
        if (t < NN) {
            float v = btn[t];
            for (int q = 0; q < HH; ++q) v = fmaf(s_h[q], Wtn[q * NN + t], v);
            s_tn[t] = fmaxf(fmaf(g_tn[t] * rinv, v, b_tn[t]), 0.f);
        }
        __syncthreads();
        if (t < 128) {
            float acc = 0.f;
            for (int n = 0; n < NN; ++n) acc = fmaf(s_tn[n], Wg1[(NN + n) * HH + t], acc);
            u1[b * HH + t] = acc;
        }
        if (t == 0) {
            float tp = 0.f;
            for (int q = 0; q < HH; ++q) tp = fmaf(s_h[q], We1[HH + q], tp);
            float K = 0.f;
            for (int hh = 0; hh < HH; ++hh)
                K += (be0[hh] * g_e0[hh] * rinv + b_e0[hh]) * We1[hh];
            Dfull[b] = tp + K + be1[0];
        }
        return;
    }
    // ---- vi/vj ----
    if (t < 128) {
        sBuf[t] = g_e0[t] * We1[t] * rinv;
    }
    __syncthreads();
    if (t < 128) {
        float a = 0.f, cc = 0.f;
        for (int hh = 0; hh < HH; ++hh) {
            a = fmaf(We0[t * HH + hh], sBuf[hh], a);
            cc = fmaf(We0[(HH + t) * HH + hh], sBuf[hh], cc);
        }
        vi[t] = a;
        vj[t] = cc;
    }
}

// ============ layer 1: out = relu(bn(Ah@W1tile + rs*u1 + bg1)) ============
// block 256 = (c8=t&7, ig=t>>3 in 0..31); thread tile 4 rows x 2 cols.
__global__ __launch_bounds__(256) void k_l1(
    const float* __restrict__ Ah, const float* __restrict__ Wg1,
    const float* __restrict__ u1, const float* __restrict__ rs,
    const float* __restrict__ bg1, const float* __restrict__ g1,
    const float* __restrict__ bb1, float* __restrict__ out) {
    __shared__ float sZ[HC * 108];
    const int b = blockIdx.y, hc = blockIdx.x * HC;
    const int t = threadIdx.x, c8 = t & 7, ig = t >> 3;
    {
        const int c = t & 15, j0 = t >> 4;
        for (int j = j0; j < NN; j += 16) sZ[c * 108 + j] = Wg1[j * HH + hc + c];
    }
    __syncthreads();
    const float* __restrict__ Ab = Ah + b * NN * NN;
    const int r3 = (ig < 4) ? 96 + ig : ig;
    float acc[4][2];
#pragma unroll
    for (int q = 0; q < 4; ++q) { acc[q][0] = 0.f; acc[q][1] = 0.f; }
    for (int j = 0; j < NN; j += 4) {
        float4 z0 = *(const float4*)&sZ[c8 * 108 + j];
        float4 z1 = *(const float4*)&sZ[(c8 + 8) * 108 + j];
        float4 av[4];
        av[0] = *(const float4*)(Ab + ig * NN + j);
        av[1] = *(const float4*)(Ab + (ig + 32) * NN + j);
        av[2] = *(const float4*)(Ab + (ig + 64) * NN + j);
        av[3] = *(const float4*)(Ab + r3 * NN + j);
#pragma unroll
        for (int q = 0; q < 4; ++q) {
            acc[q][0] = fmaf(av[q].x, z0.x, acc[q][0]);
            acc[q][0] = fmaf(av[q].y, z0.y, acc[q][0]);
            acc[q][0] = fmaf(av[q].z, z0.z, acc[q][0]);
            acc[q][0] = fmaf(av[q].w, z0.w, acc[q][0]);
            acc[q][1] = fmaf(av[q].x, z1.x, acc[q][1]);
            acc[q][1] = fmaf(av[q].y, z1.y, acc[q][1]);
            acc[q][1] = fmaf(av[q].z, z1.z, acc[q][1]);
            acc[q][1] = fmaf(av[q].w, z1.w, acc[q][1]);
        }
    }
    const float rinv = 1.0f / sqrtf(1.f + EPSBN);
    const int h0 = hc + c8, h1 = hc + c8 + 8;
    const float gs0 = g1[h0] * rinv, gs1 = g1[h1] * rinv;
    const float bv0 = bb1[h0], bv1 = bb1[h1];
    const float bg0 = bg1[h0], bg1v = bg1[h1];
    const float u0 = u1[b * HH + h0], u1v = u1[b * HH + h1];
    float* ob = out + b * NN * HH;
#pragma unroll
    for (int q = 0; q < 4; ++q) {
        const int i = (q == 3) ? r3 : ig + 32 * q;
        const bool valid = (q < 3) || (ig < 4);
        if (valid) {
            float rsv = rs[b * NN + i];
            float y0 = fmaxf(fmaf(gs0, acc[q][0] + rsv * u0 + bg0, bv0), 0.f);
            float y1 = fmaxf(fmaf(gs1, acc[q][1] + rsv * u1v + bg1v, bv1), 0.f);
            ob[i * HH + h0] = y0;
            ob[i * HH + h1] = y1;
        }
    }
}

// ============ fused layer: z = x@Wtile -> LDS; out = relu(bn(Ah@z + bg)) ============
template <bool LAST>
__global__ __launch_bounds__(256) void k_layer(
    const float* __restrict__ Ah, const float* __restrict__ xin,
    const float* __restrict__ W, const float* __restrict__ bg,
    const float* __restrict__ g, const float* __restrict__ bb,
    const float* __restrict__ vi, const float* __restrict__ vj,
    float* __restrict__ out, float* __restrict__ psi, float* __restrict__ psj) {
    __shared__ float sW[HC * 132];
    __shared__ float sZ[HC * 108];
    const int b = blockIdx.y, hcb = blockIdx.x, hc = hcb * HC;
    const int t = threadIdx.x, c8 = t & 7, ig = t >> 3;
    {
        const int c = t & 15, k0 = t >> 4;
        for (int k = k0; k < HH; k += 16) sW[c * 132 + k] = W[k * HH + hc + c];
    }
    __syncthreads();
    const float* __restrict__ xb = xin + b * NN * HH;
    const int r3 = (ig < 4) ? 96 + ig : ig;
    float acc[4][2];
#pragma unroll
    for (int q = 0; q < 4; ++q) { acc[q][0] = 0.f; acc[q][1] = 0.f; }
    for (int k = 0; k < HH; k += 4) {
        float4 w0 = *(const float4*)&sW[c8 * 132 + k];
        float4 w1 = *(const float4*)&sW[(c8 + 8) * 132 + k];
        float4 xv[4];
        xv[0] = *(const float4*)(xb + ig * HH + k);
        xv[1] = *(const float4*)(xb + (ig + 32) * HH + k);
        xv[2] = *(const float4*)(xb + (ig + 64) * HH + k);
        xv[3] = *(const float4*)(xb + r3 * HH + k);
#pragma unroll
        for (int q = 0; q < 4; ++q) {
            acc[q][0] = fmaf(xv[q].x, w0.x, acc[q][0]);
            acc[q][0] = fmaf(xv[q].y, w0.y, acc[q][0]);
            acc[q][0] = fmaf(xv[q].z, w0.z, acc[q][0]);
            acc[q][0] = fmaf(xv[q].w, w0.w, acc[q][0]);
            acc[q][1] = fmaf(xv[q].x, w1.x, acc[q][1]);
            acc[q][1] = fmaf(xv[q].y, w1.y, acc[q][1]);
            acc[q][1] = fmaf(xv[q].z, w1.z, acc[q][1]);
            acc[q][1] = fmaf(xv[q].w, w1.w, acc[q][1]);
        }
    }
#pragma unroll
    for (int q = 0; q < 4; ++q) {
        const int i = (q == 3) ? r3 : ig + 32 * q;
        if ((q < 3) || (ig < 4)) {
            sZ[c8 * 108 + i] = acc[q][0];
            sZ[(c8 + 8) * 108 + i] = acc[q][1];
        }
    }
    __syncthreads();
#pragma unroll
    for (int q = 0; q < 4; ++q) { acc[q][0] = 0.f; acc[q][1] = 0.f; }
    const float* __restrict__ Ab = Ah + b * NN * NN;
    for (int j = 0; j < NN; j += 4) {
        float4 z0 = *(const float4*)&sZ[c8 * 108 + j];
        float4 z1 = *(const float4*)&sZ[(c8 + 8) * 108 + j];
        float4 av[4];
        av[0] = *(const float4*)(Ab + ig * NN + j);
        av[1] = *(const float4*)(Ab + (ig + 32) * NN + j);
        av[2] = *(const float4*)(Ab + (ig + 64) * NN + j);
        av[3] = *(const float4*)(Ab + r3 * NN + j);
#pragma unroll
        for (int q = 0; q < 4; ++q) {
            acc[q][0] = fmaf(av[q].x, z0.x, acc[q][0]);
            acc[q][0] = fmaf(av[q].y, z0.y, acc[q][0]);
            acc[q][0] = fmaf(av[q].z, z0.z, acc[q][0]);
            acc[q][0] = fmaf(av[q].w, z0.w, acc[q][0]);
            acc[q][1] = fmaf(av[q].x, z1.x, acc[q][1]);
            acc[q][1] = fmaf(av[q].y, z1.y, acc[q][1]);
            acc[q][1] = fmaf(av[q].z, z1.z, acc[q][1]);
            acc[q][1] = fmaf(av[q].w, z1.w, acc[q][1]);
        }
    }
    const float rinv = 1.0f / sqrtf(1.f + EPSBN);
    const int h0 = hc + c8, h1 = hc + c8 + 8;
    const float gs0 = g[h0] * rinv, gs1 = g[h1] * rinv;
    const float bv0 = bb[h0], bv1 = bb[h1];
    const float bg0 = bg[h0], bg1v = bg[h1];
    float vih0 = 0.f, vih1 = 0.f, vjh0 = 0.f, vjh1 = 0.f;
    if (LAST) { vih0 = vi[h0]; vih1 = vi[h1]; vjh0 = vj[h0]; vjh1 = vj[h1]; }
    float* ob = LAST ? nullptr : out + b * NN * HH;
#pragma unroll
    for (int q = 0; q < 4; ++q) {
        const int i = (q == 3) ? r3 : ig + 32 * q;
        const bool valid = (q < 3) || (ig < 4);
        float y0 = fmaxf(fmaf(gs0, acc[q][0] + bg0, bv0), 0.f);
        float y1 = fmaxf(fmaf(gs1, acc[q][1] + bg1v, bv1), 0.f);
        if (LAST) {
            float pi = fmaf(y0, vih0, y1 * vih1);
            float pj = fmaf(y0, vjh0, y1 * vjh1);
            pi += __shfl_xor(pi, 1, 8);
            pi += __shfl_xor(pi, 2, 8);
            pi += __shfl_xor(pi, 4, 8);
            pj += __shfl_xor(pj, 1, 8);
            pj += __shfl_xor(pj, 2, 8);
            pj += __shfl_xor(pj, 4, 8);
            if (c8 == 0 && valid) {
                psi[(b * NN + i) * NCH + hcb] = pi;
                psj[(b * NN + i) * NCH + hcb] = pj;
            }
        } else if (valid) {
            ob[i * HH + h0] = y0;
            ob[i * HH + h1] = y1;
        }
    }
}

// ============ out[b,i,j] = (i!=j) * bn(si+sj+D) ============
__global__ __launch_bounds__(256) void k_out(
    const float* __restrict__ psi, const float* __restrict__ psj,
    const float* __restrict__ Dfull, const float* __restrict__ g_e1,
    const float* __restrict__ b_e1, float* __restrict__ outp) {
    __shared__ float ssi[25], ssj[NN];
    const int b = blockIdx.y, i0 = blockIdx.x * 25;
    const int t = threadIdx.x;
    if (t < NN) {
        float s = 0.f;
        const float* p = psj + (b * NN + t) * NCH;
#pragma unroll
        for (int q = 0; q < NCH; ++q) s += p[q];
        ssj[t] = s;
    }
    if (t >= 128 && t < 128 + 25) {
        int i = t - 128;
        float s = 0.f;
        const float* p = psi + (b * NN + i0 + i) * NCH;
#pragma unroll
        for (int q = 0; q < NCH; ++q) s += p[q];
        ssi[i] = s;
    }
    __syncthreads();
    const float rinv = 1.0f / sqrtf(1.f + EPSBN);
    const float D = Dfull[b], ge = g_e1[0] * rinv, be = b_e1[0];
    float* ob = outp + b * NN * NN + i0 * NN;
    for (int e = t; e < 25 * NN; e += 256) {
        int ii = e / NN, j = e - ii * NN;
        float v = fmaf(ge, ssi[ii] + ssj[j] + D, be);
        ob[e] = (i0 + ii == j) ? 0.f : v;
    }
}

extern "C" void kernel_launch(void* const* d_in, const int* in_sizes, int n_in,
                              void* d_out, int out_size, void* d_ws, size_t ws_size,
                              hipStream_t stream) {
    const float* X    = (const float*)d_in[0];
    const float* timev= (const float*)d_in[1];
    const float* Wt1  = (const float*)d_in[2];
    const float* bt1  = (const float*)d_in[3];
    const float* Wt2  = (const float*)d_in[4];
    const float* bt2  = (const float*)d_in[5];
    const float* Wtn  = (const float*)d_in[6];
    const float* btn  = (const float*)d_in[7];
    const float* g_tn = (const float*)d_in[8];
    const float* b_tn = (const float*)d_in[9];
    const float* Wg1  = (const float*)d_in[10];
    const float* bg1  = (const float*)d_in[11];
    const float* g1   = (const float*)d_in[12];
    const float* bb1  = (const float*)d_in[13];
    const float* Wg2  = (const float*)d_in[14];
    const float* bg2  = (const float*)d_in[15];
    const float* g2   = (const float*)d_in[16];
    const float* bb2  = (const float*)d_in[17];
    const float* Wg3  = (const float*)d_in[18];
    const float* bg3  = (const float*)d_in[19];
    const float* g3   = (const float*)d_in[20];
    const float* bb3  = (const float*)d_in[21];
    const float* We0  = (const float*)d_in[22];
    const float* be0  = (const float*)d_in[23];
    const float* g_e0 = (const float*)d_in[24];
    const float* b_e0 = (const float*)d_in[25];
    const float* We1  = (const float*)d_in[26];
    const float* be1  = (const float*)d_in[27];
    const float* g_e1 = (const float*)d_in[28];
    const float* b_e1 = (const float*)d_in[29];

    float* ws = (float*)d_ws;
    float* Ah    = ws;            // 640000
    float* rs    = Ah + 640000;   // 6400
    float* u1    = rs + 6400;     // 8192
    float* Dfull = u1 + 8192;     // 64
    float* vi    = Dfull + 64;    // 128
    float* vj    = vi + 128;      // 128
    float* x1    = vj + 128;      // 819200 (dead after layer2 -> psi/psj alias)
    float* x2    = x1 + 819200;   // 819200
    float* psi   = x1;            // 51200
    float* psj   = x1 + 51200;    // 51200

    k_setup<<<dim3(4 * NB + NB + 1), dim3(256), 0, stream>>>(
        X, timev, Wt1, bt1, Wt2, bt2, Wtn, btn, g_tn, b_tn, Wg1, We0, We1, be1,
        be0, g_e0, b_e0, Ah, rs, u1, Dfull, vi, vj);

    k_l1<<<dim3(NCH, NB), dim3(256), 0, stream>>>(Ah, Wg1, u1, rs, bg1, g1, bb1, x1);
    k_layer<false><<<dim3(NCH, NB), dim3(256), 0, stream>>>(Ah, x1, Wg2, bg2, g2, bb2,
                                                            nullptr, nullptr, x2,
                                                            nullptr, nullptr);
    k_layer<true><<<dim3(NCH, NB), dim3(256), 0, stream>>>(Ah, x2, Wg3, bg3, g3, bb3,
                                                           vi, vj, nullptr, psi, psj);

    k_out<<<dim3(4, NB), dim3(256), 0, stream>>>(psi, psj, Dfull, g_e1, b_e1,
                                                 (float*)d_out);
}